// Round 19
// baseline (241.088 us; speedup 1.0000x reference)
//
#include <hip/hip_runtime.h>
#include <hip/hip_bf16.h>
#include <cstdint>
#include <cstddef>

#define DDIM 1024
#define BROWS 32768

typedef __attribute__((ext_vector_type(8))) short short8;
typedef __attribute__((ext_vector_type(4))) float floatx4;

__device__ __forceinline__ float bf2f(unsigned short u) {
  return __uint_as_float(((unsigned int)u) << 16);
}
__device__ __forceinline__ unsigned short f2bf(float f) {
  unsigned int u = __float_as_uint(f);
  u += 0x7FFFu + ((u >> 16) & 1u);
  return (unsigned short)(u >> 16);
}

__device__ __forceinline__ void load_lds16(const void* g, void* l) {
  __builtin_amdgcn_global_load_lds(
      (const __attribute__((address_space(1))) unsigned int*)g,
      (__attribute__((address_space(3))) unsigned int*)l,
      16, 0, 0);
}

// ===========================================================================
// Big GEMM: Out = (x @ W) * inv + bias.
// R18 kernel body (BM=128 x BN=256, 512 thr, serial 2-barrier, scattered
// stores — 130 us / FETCH 180 MB) with a SUPERTILE mapping: groups of
// 64 m-panels x all 4 n-tiles. An x panel's 4 consumers are 64 dispatch
// slots apart (L3-hot, not simultaneous); live x working set ~64 MB << L3.
// Targets the remaining ~48 MB x-refetch. Kernel body unchanged.
// ===========================================================================
__global__ void __launch_bounds__(512, 2)
big_gemm(const float* __restrict__ Af, const unsigned short* __restrict__ Bt,
         float* __restrict__ Outf, const float* __restrict__ inv_ptr,
         const float* __restrict__ bias)
{
  __shared__ unsigned short As[128 * 32];  // 8 KB
  __shared__ unsigned short Bs[256 * 32];  // 16 KB

  const int tid  = threadIdx.x;
  const int lane = tid & 63;
  const int wid  = tid >> 6;              // 0..7
  const int wr = wid >> 2, wc = wid & 3;  // 2 x 4 wave grid
  const int g = lane >> 4, r = lane & 15;

  // supertile mapping: group = 64 m-panels x 4 n-tiles (256 blocks/group)
  const int b     = (int)blockIdx.x;
  const int grp   = b >> 8;          // 0..3
  const int nidx  = (b & 255) >> 6;  // 0..3
  const int m_in  = b & 63;          // 0..63
  const int bm0 = ((grp << 6) + m_in) * 128;
  const int bn0 = nidx * 256;

  const floatx4 zero4 = {0.f, 0.f, 0.f, 0.f};
  floatx4 acc[4][4];
#pragma unroll
  for (int m = 0; m < 4; ++m)
#pragma unroll
    for (int n = 0; n < 4; ++n) acc[m][n] = zero4;

  for (int kk = 0; kk < DDIM; kk += 32) {
    __syncthreads();
    // stage B tile 256x32 (bf16, async direct-to-LDS): 2 passes x 512 thr
#pragma unroll
    for (int p = 0; p < 2; ++p) {
      const int o = p * 8192 + tid * 16;  // byte offset in tile
      const int row = o >> 6;             // 64B per row (32 bf16)
      const int cole = (o & 63) >> 1;     // element col (0,8,16,24)
      load_lds16(Bt + (size_t)(bn0 + row) * DDIM + kk + cole, (char*)Bs + o);
    }
    // stage A tile 128x32: f32 -> bf16 reg-convert, 1 pass x 512 thr
    {
      const int o = tid * 16;
      const int row = o >> 6;
      const int cole = (o & 63) >> 1;
      const float4* s = (const float4*)(Af + (size_t)(bm0 + row) * DDIM + kk + cole);
      float4 x0 = s[0], x1 = s[1];
      short8 t;
      t[0] = (short)f2bf(x0.x); t[1] = (short)f2bf(x0.y);
      t[2] = (short)f2bf(x0.z); t[3] = (short)f2bf(x0.w);
      t[4] = (short)f2bf(x1.x); t[5] = (short)f2bf(x1.y);
      t[6] = (short)f2bf(x1.z); t[7] = (short)f2bf(x1.w);
      *(short8*)((char*)As + o) = t;
    }
    __syncthreads();

    short8 afr[4], bfr[4];
#pragma unroll
    for (int m = 0; m < 4; ++m)
      afr[m] = *(const short8*)((const char*)As + (wr * 64 + m * 16 + r) * 64 + g * 16);
#pragma unroll
    for (int n = 0; n < 4; ++n)
      bfr[n] = *(const short8*)((const char*)Bs + (wc * 64 + n * 16 + r) * 64 + g * 16);
#pragma unroll
    for (int m = 0; m < 4; ++m)
#pragma unroll
      for (int n = 0; n < 4; ++n)
        acc[m][n] = __builtin_amdgcn_mfma_f32_16x16x32_bf16(afr[m], bfr[n], acc[m][n], 0, 0, 0);
  }

  // Epilogue: plain scattered stores (no RMW in practice — R13/R18 counters).
  const float inv = *inv_ptr;
#pragma unroll
  for (int n = 0; n < 4; ++n) {
    const int ocol = bn0 + wc * 64 + n * 16 + r;
    const float bv = bias[ocol];
#pragma unroll
    for (int m = 0; m < 4; ++m) {
      const int orow0 = bm0 + wr * 64 + m * 16 + g * 4;
#pragma unroll
      for (int q = 0; q < 4; ++q) {
        Outf[(size_t)(orow0 + q) * DDIM + ocol] = acc[m][n][q] * inv + bv;
      }
    }
  }
}

// ===========================================================================
// Small square GEMM (1024^3): 64x64 tiles, grid 256 (verified R9-R18).
// ===========================================================================
__global__ void __launch_bounds__(256, 2)
sq_gemm(const unsigned short* __restrict__ A, const unsigned short* __restrict__ Bt,
        unsigned short* __restrict__ Out, const float* __restrict__ in_max,
        float* __restrict__ out_max)
{
  __shared__ __align__(16) unsigned short As[2][4096];  // [64][64] bf16 = 8 KB/buf
  __shared__ __align__(16) unsigned short Bs[2][4096];
  __shared__ float redw[4];

  const int tid  = threadIdx.x;
  const int lane = tid & 63;
  const int wid  = tid >> 6;
  const int wr = wid >> 1, wc = wid & 1;
  const int g = lane >> 4, r = lane & 15;

  const int bm0 = (int)(blockIdx.x >> 4) * 64;
  const int bn0 = (int)(blockIdx.x & 15) * 64;

  const int so    = tid * 16;          // 0..4080
  const int srow0 = so >> 7;           // 0..31 (row within half; half 1 = +32)
  const int sc16  = (so >> 4) & 7;     // 16B chunk in 128B row
  const int scs   = sc16 ^ (srow0 & 7); // pre-swizzled source chunk
  const unsigned short* aSrc0 = A  + (size_t)(bm0 + srow0) * DDIM + scs * 8;
  const unsigned short* aSrc1 = A  + (size_t)(bm0 + 32 + srow0) * DDIM + scs * 8;
  const unsigned short* bSrc0 = Bt + (size_t)(bn0 + srow0) * DDIM + scs * 8;
  const unsigned short* bSrc1 = Bt + (size_t)(bn0 + 32 + srow0) * DDIM + scs * 8;

  const floatx4 zero4 = {0.f, 0.f, 0.f, 0.f};
  floatx4 acc[2][2];
#pragma unroll
  for (int fm = 0; fm < 2; ++fm)
#pragma unroll
    for (int fn = 0; fn < 2; ++fn) acc[fm][fn] = zero4;

  load_lds16(aSrc0, (char*)&As[0][0] + so);
  load_lds16(aSrc1, (char*)&As[0][0] + 4096 + so);
  load_lds16(bSrc0, (char*)&Bs[0][0] + so);
  load_lds16(bSrc1, (char*)&Bs[0][0] + 4096 + so);
  __syncthreads();

  int buf = 0;
  for (int t = 0; t < 16; ++t) {
    if (t + 1 < 16) {
      const int kk = (t + 1) * 64;
      load_lds16(aSrc0 + kk, (char*)&As[buf ^ 1][0] + so);
      load_lds16(aSrc1 + kk, (char*)&As[buf ^ 1][0] + 4096 + so);
      load_lds16(bSrc0 + kk, (char*)&Bs[buf ^ 1][0] + so);
      load_lds16(bSrc1 + kk, (char*)&Bs[buf ^ 1][0] + 4096 + so);
    }
#pragma unroll
    for (int ks = 0; ks < 2; ++ks) {
      const int chunk = ((ks << 2) + g) ^ (r & 7);
      short8 af[2], bf[2];
#pragma unroll
      for (int fm = 0; fm < 2; ++fm) {
        const int arow = wr * 32 + fm * 16 + r;
        af[fm] = *(const short8*)((const char*)&As[buf][0] + (arow << 7) + (chunk << 4));
      }
#pragma unroll
      for (int fn = 0; fn < 2; ++fn) {
        const int brow = wc * 32 + fn * 16 + r;
        bf[fn] = *(const short8*)((const char*)&Bs[buf][0] + (brow << 7) + (chunk << 4));
      }
#pragma unroll
      for (int fm = 0; fm < 2; ++fm)
#pragma unroll
        for (int fn = 0; fn < 2; ++fn)
          acc[fm][fn] = __builtin_amdgcn_mfma_f32_16x16x32_bf16(af[fm], bf[fn], acc[fm][fn], 0, 0, 0);
    }
    __syncthreads();
    buf ^= 1;
  }

  float c = 1.0f;
  if (in_max != nullptr) {
    int e;
    (void)frexpf(*in_max, &e);
    c = ldexpf(1.0f, -e);  // exact power of two
  }
  const float c2 = c * c;
  float lmax = 0.0f;
#pragma unroll
  for (int fm = 0; fm < 2; ++fm) {
#pragma unroll
    for (int fn = 0; fn < 2; ++fn) {
      const int ocol = bn0 + wc * 32 + fn * 16 + r;
#pragma unroll
      for (int q = 0; q < 4; ++q) {
        const int orow = bm0 + wr * 32 + fm * 16 + g * 4 + q;
        float v = acc[fm][fn][q] * c2;
        Out[(size_t)orow * DDIM + ocol] = f2bf(v);
        lmax = fmaxf(lmax, fabsf(v));
      }
    }
  }
#pragma unroll
  for (int off = 32; off > 0; off >>= 1) lmax = fmaxf(lmax, __shfl_down(lmax, off));
  if (lane == 0) redw[wid] = lmax;
  __syncthreads();
  if (tid == 0) {
    float m = fmaxf(fmaxf(redw[0], redw[1]), fmaxf(redw[2], redw[3]));
    atomicMax((unsigned int*)out_max, __float_as_uint(m));
  }
}

// WT[n][k] = bf16(W[k][n])
__global__ void __launch_bounds__(256)
transpose_bf16(const float* __restrict__ W, unsigned short* __restrict__ WT)
{
  __shared__ float tile[64][65];
  const int bx = blockIdx.x & 15;
  const int by = blockIdx.x >> 4;
  const int tid = threadIdx.x;
  const int c = tid & 63;
  const int r0 = tid >> 6;
#pragma unroll
  for (int p = 0; p < 16; ++p) {
    int kr = p * 4 + r0;
    tile[kr][c] = W[(size_t)(bx * 64 + kr) * DDIM + by * 64 + c];
  }
  __syncthreads();
#pragma unroll
  for (int p = 0; p < 16; ++p) {
    int nr = p * 4 + r0;
    WT[(size_t)(by * 64 + nr) * DDIM + bx * 64 + c] = f2bf(tile[c][nr]);
  }
}

// vout[j] = 2^-12 * sum_i vin[i] * P[j][i]   (P symmetric bf16 1024x1024)
__global__ void __launch_bounds__(256)
gemv_pow(const unsigned short* __restrict__ P, const float* __restrict__ vin,
         float* __restrict__ vout)
{
  const int tid = threadIdx.x;
  const int lane = tid & 63;
  const int wid = tid >> 6;
  float vs[16];
  const float4* vv = (const float4*)(vin + lane * 16);
#pragma unroll
  for (int i = 0; i < 4; ++i) {
    float4 t = vv[i];
    vs[i * 4 + 0] = t.x; vs[i * 4 + 1] = t.y; vs[i * 4 + 2] = t.z; vs[i * 4 + 3] = t.w;
  }
#pragma unroll
  for (int rr = 0; rr < 4; ++rr) {
    const int row = (int)blockIdx.x * 16 + wid * 4 + rr;
    const unsigned short* pr = P + (size_t)row * DDIM + lane * 16;
    short8 p0 = *(const short8*)pr;
    short8 p1 = *(const short8*)(pr + 8);
    float s = 0.f;
#pragma unroll
    for (int e = 0; e < 8; ++e) s += bf2f((unsigned short)p0[e]) * vs[e];
#pragma unroll
    for (int e = 0; e < 8; ++e) s += bf2f((unsigned short)p1[e]) * vs[8 + e];
#pragma unroll
    for (int off = 32; off > 0; off >>= 1) s += __shfl_down(s, off);
    if (lane == 0) vout[row] = s * 0x1p-12f;
  }
}

// v_un[i] = sum_j d[j] * W[i][j]; per-block ssq partial -> vpart[bid]
__global__ void __launch_bounds__(256)
v_kernel(const float* __restrict__ W, const float* __restrict__ d,
         float* __restrict__ v_un, float* __restrict__ vpart)
{
  __shared__ float wsum[4];
  const int tid = threadIdx.x;
  const int lane = tid & 63;
  const int wid = tid >> 6;
  float vs[16];
  const float4* dv = (const float4*)(d + lane * 16);
#pragma unroll
  for (int i = 0; i < 4; ++i) {
    float4 t = dv[i];
    vs[i * 4 + 0] = t.x; vs[i * 4 + 1] = t.y; vs[i * 4 + 2] = t.z; vs[i * 4 + 3] = t.w;
  }
  float ssq = 0.f;
#pragma unroll
  for (int rr = 0; rr < 4; ++rr) {
    const int row = (int)blockIdx.x * 16 + wid * 4 + rr;
    const float4* wrow = (const float4*)(W + (size_t)row * DDIM + lane * 16);
    float s = 0.f;
#pragma unroll
    for (int i = 0; i < 4; ++i) {
      float4 t = wrow[i];
      s += t.x * vs[i * 4 + 0] + t.y * vs[i * 4 + 1] + t.z * vs[i * 4 + 2] + t.w * vs[i * 4 + 3];
    }
#pragma unroll
    for (int off = 32; off > 0; off >>= 1) s += __shfl_down(s, off);
    if (lane == 0) { v_un[row] = s; ssq += s * s; }
  }
  if (lane == 0) wsum[wid] = ssq;
  __syncthreads();
  if (tid == 0) vpart[blockIdx.x] = (wsum[0] + wsum[1]) + (wsum[2] + wsum[3]);
}

// t[j] = sum_i v_un[i]*W[i][j]; tpart[bid] = ssq over this block's 32 cols.
// Last-arriving block (atomic ticket) computes sigma -> inv (merged finalize).
__global__ void __launch_bounds__(256)
t_fin_kernel(const float* __restrict__ W, const float* __restrict__ v_un,
             float* __restrict__ vpart, float* __restrict__ tpart,
             unsigned int* __restrict__ counter, float* __restrict__ inv_out)
{
  __shared__ float part[8][33];
  __shared__ unsigned int sticket;
  const int tid = threadIdx.x;
  const int col = (int)blockIdx.x * 32 + (tid & 31);
  const int ch = tid >> 5;
  float s = 0.f;
  const int i0 = ch * 128;
  for (int i = i0; i < i0 + 128; ++i)
    s += v_un[i] * W[(size_t)i * DDIM + col];
  part[ch][tid & 31] = s;
  __syncthreads();
  if (tid < 32) {
    float t = 0.f;
#pragma unroll
    for (int c2 = 0; c2 < 8; ++c2) t += part[c2][tid];
    part[0][tid] = t * t;
  }
  __syncthreads();
  if (tid == 0) {
    float ss = 0.f;
#pragma unroll
    for (int c = 0; c < 32; ++c) ss += part[0][c];
    tpart[blockIdx.x] = ss;
    __threadfence();
    sticket = atomicAdd(counter, 1u);
  }
  __syncthreads();
  if (sticket == 31) {  // last block: finalize
    __threadfence();
    float val = 0.f;
    if (tid < 64)
      val = __uint_as_float(atomicOr((unsigned int*)&vpart[tid], 0u));
    part[tid >> 5][tid & 31] = val;
    __syncthreads();
    if (tid == 0) {
      float sv = 0.f;
      for (int i = 0; i < 64; ++i) sv += part[i >> 5][i & 31];
      float stq = 0.f;
      for (int i = 0; i < 32; ++i)
        stq += __uint_as_float(atomicOr((unsigned int*)&tpart[i], 0u));
      float sigma = sqrtf(stq / sv);
      inv_out[0] = (sigma > 0.9f) ? (0.9f / sigma) : 1.0f;
    }
  }
}

extern "C" void kernel_launch(void* const* d_in, const int* in_sizes, int n_in,
                              void* d_out, int out_size, void* d_ws, size_t ws_size,
                              hipStream_t stream)
{
  const float* x  = (const float*)d_in[0];
  const float* w  = (const float*)d_in[1];
  const float* b  = (const float*)d_in[2];
  const float* u0 = (const float*)d_in[3];
  float* out = (float*)d_out;

  char* ws = (char*)d_ws;
  float* scal = (float*)ws;  // [0..5] max chain, [8] inv, [16..79] vpart,
                             // [80..111] tpart, [120] ticket counter
  float* u_a  = (float*)(ws + 0x1000);
  float* u_b  = (float*)(ws + 0x2000);
  float* v_un = (float*)(ws + 0x3000);
  unsigned short* WT = (unsigned short*)(ws + 0x4000);
  unsigned short* P0 = (unsigned short*)(ws + 0x204000);
  unsigned short* P1 = (unsigned short*)(ws + 0x404000);

  hipMemsetAsync(d_ws, 0, 4096, stream);
  hipLaunchKernelGGL(transpose_bf16, dim3(256), dim3(256), 0, stream, w, WT);

  // M = W^T W, then square up to M^32   (64x64 tiles -> grid 256)
  hipLaunchKernelGGL(sq_gemm, dim3(256), dim3(256), 0, stream,
                     WT, WT, P0, (const float*)nullptr, &scal[0]);          // M
  hipLaunchKernelGGL(sq_gemm, dim3(256), dim3(256), 0, stream,
                     P0, P0, P1, &scal[0], &scal[1]);                       // M^2
  hipLaunchKernelGGL(sq_gemm, dim3(256), dim3(256), 0, stream,
                     P1, P1, P0, &scal[1], &scal[2]);                       // M^4
  hipLaunchKernelGGL(sq_gemm, dim3(256), dim3(256), 0, stream,
                     P0, P0, P1, &scal[2], &scal[3]);                       // M^8
  hipLaunchKernelGGL(sq_gemm, dim3(256), dim3(256), 0, stream,
                     P1, P1, P0, &scal[3], &scal[4]);                       // M^16
  hipLaunchKernelGGL(sq_gemm, dim3(256), dim3(256), 0, stream,
                     P0, P0, P1, &scal[4], &scal[5]);                       // M^32 -> P1

  // u = u0 * (M^32)^3  (direction of u0 M^96)
  hipLaunchKernelGGL(gemv_pow, dim3(64), dim3(256), 0, stream, P1, u0, u_a);
  hipLaunchKernelGGL(gemv_pow, dim3(64), dim3(256), 0, stream, P1, u_a, u_b);
  hipLaunchKernelGGL(gemv_pow, dim3(64), dim3(256), 0, stream, P1, u_b, u_a);

  hipLaunchKernelGGL(v_kernel, dim3(64), dim3(256), 0, stream, w, u_a, v_un, &scal[16]);
  hipLaunchKernelGGL(t_fin_kernel, dim3(32), dim3(256), 0, stream,
                     w, v_un, &scal[16], &scal[80],
                     (unsigned int*)&scal[120], &scal[8]);

  // out = (x @ W) * inv + b   (BM=128 x BN=256, supertile mapping)
  hipLaunchKernelGGL(big_gemm, dim3(1024), dim3(512), 0, stream,
                     x, WT, out, &scal[8], b);
}

// Round 20
// 226.389 us; speedup vs baseline: 1.0649x; 1.0649x over previous
//
#include <hip/hip_runtime.h>
#include <hip/hip_bf16.h>
#include <cstdint>
#include <cstddef>

#define DDIM 1024
#define BROWS 32768

typedef __attribute__((ext_vector_type(8))) short short8;
typedef __attribute__((ext_vector_type(4))) float floatx4;

__device__ __forceinline__ float bf2f(unsigned short u) {
  return __uint_as_float(((unsigned int)u) << 16);
}
__device__ __forceinline__ unsigned short f2bf(float f) {
  unsigned int u = __float_as_uint(f);
  u += 0x7FFFu + ((u >> 16) & 1u);
  return (unsigned short)(u >> 16);
}

__device__ __forceinline__ void load_lds16(const void* g, void* l) {
  __builtin_amdgcn_global_load_lds(
      (const __attribute__((address_space(1))) unsigned int*)g,
      (__attribute__((address_space(3))) unsigned int*)l,
      16, 0, 0);
}

// ===========================================================================
// Big GEMM: Out = (x @ W) * inv + bias.
// EXACTLY the R18 kernel — the measured optimum (130 us, FETCH 180 MB,
// 2.5 TB/s): BM=128 x BN=256, 512 thr (2x4 waves), serial 2-barrier staging
// BK=32, M-MAJOR mapping (bm0 = b&255, bn0 = b>>8), plain scattered stores.
// R19 proved byte-minimizing mappings (FETCH 82 MB) DROP to 1.47 TB/s:
// L3-hit reads serve this kernel's MLP slower than HBM streaming.
// DO NOT TOUCH — every neighbor in config space measured worse.
// ===========================================================================
__global__ void __launch_bounds__(512, 2)
big_gemm(const float* __restrict__ Af, const unsigned short* __restrict__ Bt,
         float* __restrict__ Outf, const float* __restrict__ inv_ptr,
         const float* __restrict__ bias)
{
  __shared__ unsigned short As[128 * 32];  // 8 KB
  __shared__ unsigned short Bs[256 * 32];  // 16 KB

  const int tid  = threadIdx.x;
  const int lane = tid & 63;
  const int wid  = tid >> 6;              // 0..7
  const int wr = wid >> 2, wc = wid & 3;  // 2 x 4 wave grid
  const int g = lane >> 4, r = lane & 15;

  const int bm0 = (int)(blockIdx.x & 255) * 128;  // m-major
  const int bn0 = (int)(blockIdx.x >> 8) * 256;

  const floatx4 zero4 = {0.f, 0.f, 0.f, 0.f};
  floatx4 acc[4][4];
#pragma unroll
  for (int m = 0; m < 4; ++m)
#pragma unroll
    for (int n = 0; n < 4; ++n) acc[m][n] = zero4;

  for (int kk = 0; kk < DDIM; kk += 32) {
    __syncthreads();
    // stage B tile 256x32 (bf16, async direct-to-LDS): 2 passes x 512 thr
#pragma unroll
    for (int p = 0; p < 2; ++p) {
      const int o = p * 8192 + tid * 16;  // byte offset in tile
      const int row = o >> 6;             // 64B per row (32 bf16)
      const int cole = (o & 63) >> 1;     // element col (0,8,16,24)
      load_lds16(Bt + (size_t)(bn0 + row) * DDIM + kk + cole, (char*)Bs + o);
    }
    // stage A tile 128x32: f32 -> bf16 reg-convert, 1 pass x 512 thr
    {
      const int o = tid * 16;
      const int row = o >> 6;
      const int cole = (o & 63) >> 1;
      const float4* s = (const float4*)(Af + (size_t)(bm0 + row) * DDIM + kk + cole);
      float4 x0 = s[0], x1 = s[1];
      short8 t;
      t[0] = (short)f2bf(x0.x); t[1] = (short)f2bf(x0.y);
      t[2] = (short)f2bf(x0.z); t[3] = (short)f2bf(x0.w);
      t[4] = (short)f2bf(x1.x); t[5] = (short)f2bf(x1.y);
      t[6] = (short)f2bf(x1.z); t[7] = (short)f2bf(x1.w);
      *(short8*)((char*)As + o) = t;
    }
    __syncthreads();

    short8 afr[4], bfr[4];
#pragma unroll
    for (int m = 0; m < 4; ++m)
      afr[m] = *(const short8*)((const char*)As + (wr * 64 + m * 16 + r) * 64 + g * 16);
#pragma unroll
    for (int n = 0; n < 4; ++n)
      bfr[n] = *(const short8*)((const char*)Bs + (wc * 64 + n * 16 + r) * 64 + g * 16);
#pragma unroll
    for (int m = 0; m < 4; ++m)
#pragma unroll
      for (int n = 0; n < 4; ++n)
        acc[m][n] = __builtin_amdgcn_mfma_f32_16x16x32_bf16(afr[m], bfr[n], acc[m][n], 0, 0, 0);
  }

  // Epilogue: plain scattered stores (no RMW in practice — R13/R18 counters).
  const float inv = *inv_ptr;
#pragma unroll
  for (int n = 0; n < 4; ++n) {
    const int ocol = bn0 + wc * 64 + n * 16 + r;
    const float bv = bias[ocol];
#pragma unroll
    for (int m = 0; m < 4; ++m) {
      const int orow0 = bm0 + wr * 64 + m * 16 + g * 4;
#pragma unroll
      for (int q = 0; q < 4; ++q) {
        Outf[(size_t)(orow0 + q) * DDIM + ocol] = acc[m][n][q] * inv + bv;
      }
    }
  }
}

// ===========================================================================
// Small square GEMM (1024^3): 64x64 tiles, grid 256 (verified R9-R18).
// ===========================================================================
__global__ void __launch_bounds__(256, 2)
sq_gemm(const unsigned short* __restrict__ A, const unsigned short* __restrict__ Bt,
        unsigned short* __restrict__ Out, const float* __restrict__ in_max,
        float* __restrict__ out_max)
{
  __shared__ __align__(16) unsigned short As[2][4096];  // [64][64] bf16 = 8 KB/buf
  __shared__ __align__(16) unsigned short Bs[2][4096];
  __shared__ float redw[4];

  const int tid  = threadIdx.x;
  const int lane = tid & 63;
  const int wid  = tid >> 6;
  const int wr = wid >> 1, wc = wid & 1;
  const int g = lane >> 4, r = lane & 15;

  const int bm0 = (int)(blockIdx.x >> 4) * 64;
  const int bn0 = (int)(blockIdx.x & 15) * 64;

  const int so    = tid * 16;          // 0..4080
  const int srow0 = so >> 7;           // 0..31 (row within half; half 1 = +32)
  const int sc16  = (so >> 4) & 7;     // 16B chunk in 128B row
  const int scs   = sc16 ^ (srow0 & 7); // pre-swizzled source chunk
  const unsigned short* aSrc0 = A  + (size_t)(bm0 + srow0) * DDIM + scs * 8;
  const unsigned short* aSrc1 = A  + (size_t)(bm0 + 32 + srow0) * DDIM + scs * 8;
  const unsigned short* bSrc0 = Bt + (size_t)(bn0 + srow0) * DDIM + scs * 8;
  const unsigned short* bSrc1 = Bt + (size_t)(bn0 + 32 + srow0) * DDIM + scs * 8;

  const floatx4 zero4 = {0.f, 0.f, 0.f, 0.f};
  floatx4 acc[2][2];
#pragma unroll
  for (int fm = 0; fm < 2; ++fm)
#pragma unroll
    for (int fn = 0; fn < 2; ++fn) acc[fm][fn] = zero4;

  load_lds16(aSrc0, (char*)&As[0][0] + so);
  load_lds16(aSrc1, (char*)&As[0][0] + 4096 + so);
  load_lds16(bSrc0, (char*)&Bs[0][0] + so);
  load_lds16(bSrc1, (char*)&Bs[0][0] + 4096 + so);
  __syncthreads();

  int buf = 0;
  for (int t = 0; t < 16; ++t) {
    if (t + 1 < 16) {
      const int kk = (t + 1) * 64;
      load_lds16(aSrc0 + kk, (char*)&As[buf ^ 1][0] + so);
      load_lds16(aSrc1 + kk, (char*)&As[buf ^ 1][0] + 4096 + so);
      load_lds16(bSrc0 + kk, (char*)&Bs[buf ^ 1][0] + so);
      load_lds16(bSrc1 + kk, (char*)&Bs[buf ^ 1][0] + 4096 + so);
    }
#pragma unroll
    for (int ks = 0; ks < 2; ++ks) {
      const int chunk = ((ks << 2) + g) ^ (r & 7);
      short8 af[2], bf[2];
#pragma unroll
      for (int fm = 0; fm < 2; ++fm) {
        const int arow = wr * 32 + fm * 16 + r;
        af[fm] = *(const short8*)((const char*)&As[buf][0] + (arow << 7) + (chunk << 4));
      }
#pragma unroll
      for (int fn = 0; fn < 2; ++fn) {
        const int brow = wc * 32 + fn * 16 + r;
        bf[fn] = *(const short8*)((const char*)&Bs[buf][0] + (brow << 7) + (chunk << 4));
      }
#pragma unroll
      for (int fm = 0; fm < 2; ++fm)
#pragma unroll
        for (int fn = 0; fn < 2; ++fn)
          acc[fm][fn] = __builtin_amdgcn_mfma_f32_16x16x32_bf16(af[fm], bf[fn], acc[fm][fn], 0, 0, 0);
    }
    __syncthreads();
    buf ^= 1;
  }

  float c = 1.0f;
  if (in_max != nullptr) {
    int e;
    (void)frexpf(*in_max, &e);
    c = ldexpf(1.0f, -e);  // exact power of two
  }
  const float c2 = c * c;
  float lmax = 0.0f;
#pragma unroll
  for (int fm = 0; fm < 2; ++fm) {
#pragma unroll
    for (int fn = 0; fn < 2; ++fn) {
      const int ocol = bn0 + wc * 32 + fn * 16 + r;
#pragma unroll
      for (int q = 0; q < 4; ++q) {
        const int orow = bm0 + wr * 32 + fm * 16 + g * 4 + q;
        float v = acc[fm][fn][q] * c2;
        Out[(size_t)orow * DDIM + ocol] = f2bf(v);
        lmax = fmaxf(lmax, fabsf(v));
      }
    }
  }
#pragma unroll
  for (int off = 32; off > 0; off >>= 1) lmax = fmaxf(lmax, __shfl_down(lmax, off));
  if (lane == 0) redw[wid] = lmax;
  __syncthreads();
  if (tid == 0) {
    float m = fmaxf(fmaxf(redw[0], redw[1]), fmaxf(redw[2], redw[3]));
    atomicMax((unsigned int*)out_max, __float_as_uint(m));
  }
}

// WT[n][k] = bf16(W[k][n])
__global__ void __launch_bounds__(256)
transpose_bf16(const float* __restrict__ W, unsigned short* __restrict__ WT)
{
  __shared__ float tile[64][65];
  const int bx = blockIdx.x & 15;
  const int by = blockIdx.x >> 4;
  const int tid = threadIdx.x;
  const int c = tid & 63;
  const int r0 = tid >> 6;
#pragma unroll
  for (int p = 0; p < 16; ++p) {
    int kr = p * 4 + r0;
    tile[kr][c] = W[(size_t)(bx * 64 + kr) * DDIM + by * 64 + c];
  }
  __syncthreads();
#pragma unroll
  for (int p = 0; p < 16; ++p) {
    int nr = p * 4 + r0;
    WT[(size_t)(by * 64 + nr) * DDIM + bx * 64 + c] = f2bf(tile[c][nr]);
  }
}

// vout[j] = 2^-12 * sum_i vin[i] * P[j][i]   (P symmetric bf16 1024x1024)
__global__ void __launch_bounds__(256)
gemv_pow(const unsigned short* __restrict__ P, const float* __restrict__ vin,
         float* __restrict__ vout)
{
  const int tid = threadIdx.x;
  const int lane = tid & 63;
  const int wid = tid >> 6;
  float vs[16];
  const float4* vv = (const float4*)(vin + lane * 16);
#pragma unroll
  for (int i = 0; i < 4; ++i) {
    float4 t = vv[i];
    vs[i * 4 + 0] = t.x; vs[i * 4 + 1] = t.y; vs[i * 4 + 2] = t.z; vs[i * 4 + 3] = t.w;
  }
#pragma unroll
  for (int rr = 0; rr < 4; ++rr) {
    const int row = (int)blockIdx.x * 16 + wid * 4 + rr;
    const unsigned short* pr = P + (size_t)row * DDIM + lane * 16;
    short8 p0 = *(const short8*)pr;
    short8 p1 = *(const short8*)(pr + 8);
    float s = 0.f;
#pragma unroll
    for (int e = 0; e < 8; ++e) s += bf2f((unsigned short)p0[e]) * vs[e];
#pragma unroll
    for (int e = 0; e < 8; ++e) s += bf2f((unsigned short)p1[e]) * vs[8 + e];
#pragma unroll
    for (int off = 32; off > 0; off >>= 1) s += __shfl_down(s, off);
    if (lane == 0) vout[row] = s * 0x1p-12f;
  }
}

// v_un[i] = sum_j d[j] * W[i][j]; per-block ssq partial -> vpart[bid]
__global__ void __launch_bounds__(256)
v_kernel(const float* __restrict__ W, const float* __restrict__ d,
         float* __restrict__ v_un, float* __restrict__ vpart)
{
  __shared__ float wsum[4];
  const int tid = threadIdx.x;
  const int lane = tid & 63;
  const int wid = tid >> 6;
  float vs[16];
  const float4* dv = (const float4*)(d + lane * 16);
#pragma unroll
  for (int i = 0; i < 4; ++i) {
    float4 t = dv[i];
    vs[i * 4 + 0] = t.x; vs[i * 4 + 1] = t.y; vs[i * 4 + 2] = t.z; vs[i * 4 + 3] = t.w;
  }
  float ssq = 0.f;
#pragma unroll
  for (int rr = 0; rr < 4; ++rr) {
    const int row = (int)blockIdx.x * 16 + wid * 4 + rr;
    const float4* wrow = (const float4*)(W + (size_t)row * DDIM + lane * 16);
    float s = 0.f;
#pragma unroll
    for (int i = 0; i < 4; ++i) {
      float4 t = wrow[i];
      s += t.x * vs[i * 4 + 0] + t.y * vs[i * 4 + 1] + t.z * vs[i * 4 + 2] + t.w * vs[i * 4 + 3];
    }
#pragma unroll
    for (int off = 32; off > 0; off >>= 1) s += __shfl_down(s, off);
    if (lane == 0) { v_un[row] = s; ssq += s * s; }
  }
  if (lane == 0) wsum[wid] = ssq;
  __syncthreads();
  if (tid == 0) vpart[blockIdx.x] = (wsum[0] + wsum[1]) + (wsum[2] + wsum[3]);
}

// t[j] = sum_i v_un[i]*W[i][j]; tpart[bid] = ssq over this block's 32 cols.
// Last-arriving block (atomic ticket) computes sigma -> inv (merged finalize).
__global__ void __launch_bounds__(256)
t_fin_kernel(const float* __restrict__ W, const float* __restrict__ v_un,
             float* __restrict__ vpart, float* __restrict__ tpart,
             unsigned int* __restrict__ counter, float* __restrict__ inv_out)
{
  __shared__ float part[8][33];
  __shared__ unsigned int sticket;
  const int tid = threadIdx.x;
  const int col = (int)blockIdx.x * 32 + (tid & 31);
  const int ch = tid >> 5;
  float s = 0.f;
  const int i0 = ch * 128;
  for (int i = i0; i < i0 + 128; ++i)
    s += v_un[i] * W[(size_t)i * DDIM + col];
  part[ch][tid & 31] = s;
  __syncthreads();
  if (tid < 32) {
    float t = 0.f;
#pragma unroll
    for (int c2 = 0; c2 < 8; ++c2) t += part[c2][tid];
    part[0][tid] = t * t;
  }
  __syncthreads();
  if (tid == 0) {
    float ss = 0.f;
#pragma unroll
    for (int c = 0; c < 32; ++c) ss += part[0][c];
    tpart[blockIdx.x] = ss;
    __threadfence();
    sticket = atomicAdd(counter, 1u);
  }
  __syncthreads();
  if (sticket == 31) {  // last block: finalize
    __threadfence();
    float val = 0.f;
    if (tid < 64)
      val = __uint_as_float(atomicOr((unsigned int*)&vpart[tid], 0u));
    part[tid >> 5][tid & 31] = val;
    __syncthreads();
    if (tid == 0) {
      float sv = 0.f;
      for (int i = 0; i < 64; ++i) sv += part[i >> 5][i & 31];
      float stq = 0.f;
      for (int i = 0; i < 32; ++i)
        stq += __uint_as_float(atomicOr((unsigned int*)&tpart[i], 0u));
      float sigma = sqrtf(stq / sv);
      inv_out[0] = (sigma > 0.9f) ? (0.9f / sigma) : 1.0f;
    }
  }
}

extern "C" void kernel_launch(void* const* d_in, const int* in_sizes, int n_in,
                              void* d_out, int out_size, void* d_ws, size_t ws_size,
                              hipStream_t stream)
{
  const float* x  = (const float*)d_in[0];
  const float* w  = (const float*)d_in[1];
  const float* b  = (const float*)d_in[2];
  const float* u0 = (const float*)d_in[3];
  float* out = (float*)d_out;

  char* ws = (char*)d_ws;
  float* scal = (float*)ws;  // [0..5] max chain, [8] inv, [16..79] vpart,
                             // [80..111] tpart, [120] ticket counter
  float* u_a  = (float*)(ws + 0x1000);
  float* u_b  = (float*)(ws + 0x2000);
  float* v_un = (float*)(ws + 0x3000);
  unsigned short* WT = (unsigned short*)(ws + 0x4000);
  unsigned short* P0 = (unsigned short*)(ws + 0x204000);
  unsigned short* P1 = (unsigned short*)(ws + 0x404000);

  hipMemsetAsync(d_ws, 0, 4096, stream);
  hipLaunchKernelGGL(transpose_bf16, dim3(256), dim3(256), 0, stream, w, WT);

  // M = W^T W, then square up to M^32   (64x64 tiles -> grid 256)
  hipLaunchKernelGGL(sq_gemm, dim3(256), dim3(256), 0, stream,
                     WT, WT, P0, (const float*)nullptr, &scal[0]);          // M
  hipLaunchKernelGGL(sq_gemm, dim3(256), dim3(256), 0, stream,
                     P0, P0, P1, &scal[0], &scal[1]);                       // M^2
  hipLaunchKernelGGL(sq_gemm, dim3(256), dim3(256), 0, stream,
                     P1, P1, P0, &scal[1], &scal[2]);                       // M^4
  hipLaunchKernelGGL(sq_gemm, dim3(256), dim3(256), 0, stream,
                     P0, P0, P1, &scal[2], &scal[3]);                       // M^8
  hipLaunchKernelGGL(sq_gemm, dim3(256), dim3(256), 0, stream,
                     P1, P1, P0, &scal[3], &scal[4]);                       // M^16
  hipLaunchKernelGGL(sq_gemm, dim3(256), dim3(256), 0, stream,
                     P0, P0, P1, &scal[4], &scal[5]);                       // M^32 -> P1

  // u = u0 * (M^32)^3  (direction of u0 M^96)
  hipLaunchKernelGGL(gemv_pow, dim3(64), dim3(256), 0, stream, P1, u0, u_a);
  hipLaunchKernelGGL(gemv_pow, dim3(64), dim3(256), 0, stream, P1, u_a, u_b);
  hipLaunchKernelGGL(gemv_pow, dim3(64), dim3(256), 0, stream, P1, u_b, u_a);

  hipLaunchKernelGGL(v_kernel, dim3(64), dim3(256), 0, stream, w, u_a, v_un, &scal[16]);
  hipLaunchKernelGGL(t_fin_kernel, dim3(32), dim3(256), 0, stream,
                     w, v_un, &scal[16], &scal[80],
                     (unsigned int*)&scal[120], &scal[8]);

  // out = (x @ W) * inv + b   (R18: BM=128 x BN=256, m-major — measured best)
  hipLaunchKernelGGL(big_gemm, dim3(1024), dim3(512), 0, stream,
                     x, WT, out, &scal[8], b);
}

// Round 21
// 224.949 us; speedup vs baseline: 1.0717x; 1.0064x over previous
//
#include <hip/hip_runtime.h>
#include <hip/hip_bf16.h>
#include <cstdint>
#include <cstddef>

#define DDIM 1024
#define BROWS 32768

typedef __attribute__((ext_vector_type(8))) short short8;
typedef __attribute__((ext_vector_type(4))) float floatx4;

__device__ __forceinline__ float bf2f(unsigned short u) {
  return __uint_as_float(((unsigned int)u) << 16);
}
__device__ __forceinline__ unsigned short f2bf(float f) {
  unsigned int u = __float_as_uint(f);
  u += 0x7FFFu + ((u >> 16) & 1u);
  return (unsigned short)(u >> 16);
}

__device__ __forceinline__ void load_lds16(const void* g, void* l) {
  __builtin_amdgcn_global_load_lds(
      (const __attribute__((address_space(1))) unsigned int*)g,
      (__attribute__((address_space(3))) unsigned int*)l,
      16, 0, 0);
}

// ===========================================================================
// Big GEMM: Out = (x @ W) * inv + bias.
// R18 geometry (BM=128 x BN=256, 512 thr 2x4 waves, m-major, scattered
// stores — measured 132 us / FETCH 181 MB / 2.45 TB/s) + R3's verified
// 1-deep double-buffer (A: f32 reg-prefetch issued early, converted late;
// B: global_load_lds into alternate buffer). At BN=256 a panel has only 4
// sharers (same XCD: b, b+256), halving the race surface that made dbuf
// over-fetch at BN=128 (R12). LDS 48 KB -> still 2 blocks/CU, 16 waves.
// ===========================================================================
__global__ void __launch_bounds__(512, 2)
big_gemm(const float* __restrict__ Af, const unsigned short* __restrict__ Bt,
         float* __restrict__ Outf, const float* __restrict__ inv_ptr,
         const float* __restrict__ bias)
{
  __shared__ __align__(16) char smem[49152];
  // As buffers: [0,8192),[8192,16384); Bs buffers: [16384,32768),[32768,49152)

  const int tid  = threadIdx.x;
  const int lane = tid & 63;
  const int wid  = tid >> 6;              // 0..7
  const int wr = wid >> 2, wc = wid & 3;  // 2 x 4 wave grid
  const int g = lane >> 4, r = lane & 15;

  const int bm0 = (int)(blockIdx.x & 255) * 128;  // m-major
  const int bn0 = (int)(blockIdx.x >> 8) * 256;

  const floatx4 zero4 = {0.f, 0.f, 0.f, 0.f};
  floatx4 acc[4][4];
#pragma unroll
  for (int m = 0; m < 4; ++m)
#pragma unroll
    for (int n = 0; n < 4; ++n) acc[m][n] = zero4;

  // per-thread staging geometry
  const int ao   = tid * 16;            // A: one pass, byte offset in 8 KB
  const int arow = ao >> 6;             // 64B per row (32 bf16 / 32 f32 src of 8)
  const int acol = (ao & 63) >> 1;      // element col (0,8,16,24)
  const float* aSrc = Af + (size_t)(bm0 + arow) * DDIM + acol;

  // prologue: stage K-tile 0 into buffer 0
  {
#pragma unroll
    for (int p = 0; p < 2; ++p) {
      const int o = p * 8192 + tid * 16;
      const int row = o >> 6;
      const int cole = (o & 63) >> 1;
      load_lds16(Bt + (size_t)(bn0 + row) * DDIM + cole, smem + 16384 + o);
    }
    float4 x0 = *(const float4*)aSrc;
    float4 x1 = *(const float4*)(aSrc + 4);
    short8 t;
    t[0] = (short)f2bf(x0.x); t[1] = (short)f2bf(x0.y);
    t[2] = (short)f2bf(x0.z); t[3] = (short)f2bf(x0.w);
    t[4] = (short)f2bf(x1.x); t[5] = (short)f2bf(x1.y);
    t[6] = (short)f2bf(x1.z); t[7] = (short)f2bf(x1.w);
    *(short8*)(smem + ao) = t;
  }
  __syncthreads();

  for (int t = 0; t < 32; ++t) {
    const int co = t & 1;
    char* curA = smem + co * 8192;
    char* curB = smem + 16384 + co * 16384;
    char* nxtA = smem + (co ^ 1) * 8192;
    char* nxtB = smem + 16384 + (co ^ 1) * 16384;

    float4 pa0, pa1;
    const bool pref = (t < 31);
    if (pref) {
      const int ko = (t + 1) * 32;
#pragma unroll
      for (int p = 0; p < 2; ++p) {
        const int o = p * 8192 + tid * 16;
        const int row = o >> 6;
        const int cole = (o & 63) >> 1;
        load_lds16(Bt + (size_t)(bn0 + row) * DDIM + ko + cole, nxtB + o);
      }
      pa0 = *(const float4*)(aSrc + ko);      // issued early, consumed late
      pa1 = *(const float4*)(aSrc + ko + 4);
    }

    short8 afr[4], bfr[4];
#pragma unroll
    for (int m = 0; m < 4; ++m)
      afr[m] = *(const short8*)(curA + (wr * 64 + m * 16 + r) * 64 + g * 16);
#pragma unroll
    for (int n = 0; n < 4; ++n)
      bfr[n] = *(const short8*)(curB + (wc * 64 + n * 16 + r) * 64 + g * 16);
#pragma unroll
    for (int m = 0; m < 4; ++m)
#pragma unroll
      for (int n = 0; n < 4; ++n)
        acc[m][n] = __builtin_amdgcn_mfma_f32_16x16x32_bf16(afr[m], bfr[n], acc[m][n], 0, 0, 0);

    if (pref) {
      short8 tt;
      tt[0] = (short)f2bf(pa0.x); tt[1] = (short)f2bf(pa0.y);
      tt[2] = (short)f2bf(pa0.z); tt[3] = (short)f2bf(pa0.w);
      tt[4] = (short)f2bf(pa1.x); tt[5] = (short)f2bf(pa1.y);
      tt[6] = (short)f2bf(pa1.z); tt[7] = (short)f2bf(pa1.w);
      *(short8*)(nxtA + ao) = tt;
    }
    __syncthreads();  // drains gload_lds (nxtB) + ds_writes (nxtA)
  }

  // Epilogue: plain scattered stores (no RMW in practice — R13/R18 counters).
  const float inv = *inv_ptr;
#pragma unroll
  for (int n = 0; n < 4; ++n) {
    const int ocol = bn0 + wc * 64 + n * 16 + r;
    const float bv = bias[ocol];
#pragma unroll
    for (int m = 0; m < 4; ++m) {
      const int orow0 = bm0 + wr * 64 + m * 16 + g * 4;
#pragma unroll
      for (int q = 0; q < 4; ++q) {
        Outf[(size_t)(orow0 + q) * DDIM + ocol] = acc[m][n][q] * inv + bv;
      }
    }
  }
}

// ===========================================================================
// Small square GEMM (1024^3): 64x64 tiles, grid 256 (verified R9-R20).
// ===========================================================================
__global__ void __launch_bounds__(256, 2)
sq_gemm(const unsigned short* __restrict__ A, const unsigned short* __restrict__ Bt,
        unsigned short* __restrict__ Out, const float* __restrict__ in_max,
        float* __restrict__ out_max)
{
  __shared__ __align__(16) unsigned short As[2][4096];  // [64][64] bf16 = 8 KB/buf
  __shared__ __align__(16) unsigned short Bs[2][4096];
  __shared__ float redw[4];

  const int tid  = threadIdx.x;
  const int lane = tid & 63;
  const int wid  = tid >> 6;
  const int wr = wid >> 1, wc = wid & 1;
  const int g = lane >> 4, r = lane & 15;

  const int bm0 = (int)(blockIdx.x >> 4) * 64;
  const int bn0 = (int)(blockIdx.x & 15) * 64;

  const int so    = tid * 16;          // 0..4080
  const int srow0 = so >> 7;           // 0..31 (row within half; half 1 = +32)
  const int sc16  = (so >> 4) & 7;     // 16B chunk in 128B row
  const int scs   = sc16 ^ (srow0 & 7); // pre-swizzled source chunk
  const unsigned short* aSrc0 = A  + (size_t)(bm0 + srow0) * DDIM + scs * 8;
  const unsigned short* aSrc1 = A  + (size_t)(bm0 + 32 + srow0) * DDIM + scs * 8;
  const unsigned short* bSrc0 = Bt + (size_t)(bn0 + srow0) * DDIM + scs * 8;
  const unsigned short* bSrc1 = Bt + (size_t)(bn0 + 32 + srow0) * DDIM + scs * 8;

  const floatx4 zero4 = {0.f, 0.f, 0.f, 0.f};
  floatx4 acc[2][2];
#pragma unroll
  for (int fm = 0; fm < 2; ++fm)
#pragma unroll
    for (int fn = 0; fn < 2; ++fn) acc[fm][fn] = zero4;

  load_lds16(aSrc0, (char*)&As[0][0] + so);
  load_lds16(aSrc1, (char*)&As[0][0] + 4096 + so);
  load_lds16(bSrc0, (char*)&Bs[0][0] + so);
  load_lds16(bSrc1, (char*)&Bs[0][0] + 4096 + so);
  __syncthreads();

  int buf = 0;
  for (int t = 0; t < 16; ++t) {
    if (t + 1 < 16) {
      const int kk = (t + 1) * 64;
      load_lds16(aSrc0 + kk, (char*)&As[buf ^ 1][0] + so);
      load_lds16(aSrc1 + kk, (char*)&As[buf ^ 1][0] + 4096 + so);
      load_lds16(bSrc0 + kk, (char*)&Bs[buf ^ 1][0] + so);
      load_lds16(bSrc1 + kk, (char*)&Bs[buf ^ 1][0] + 4096 + so);
    }
#pragma unroll
    for (int ks = 0; ks < 2; ++ks) {
      const int chunk = ((ks << 2) + g) ^ (r & 7);
      short8 af[2], bf[2];
#pragma unroll
      for (int fm = 0; fm < 2; ++fm) {
        const int arow = wr * 32 + fm * 16 + r;
        af[fm] = *(const short8*)((const char*)&As[buf][0] + (arow << 7) + (chunk << 4));
      }
#pragma unroll
      for (int fn = 0; fn < 2; ++fn) {
        const int brow = wc * 32 + fn * 16 + r;
        bf[fn] = *(const short8*)((const char*)&Bs[buf][0] + (brow << 7) + (chunk << 4));
      }
#pragma unroll
      for (int fm = 0; fm < 2; ++fm)
#pragma unroll
        for (int fn = 0; fn < 2; ++fn)
          acc[fm][fn] = __builtin_amdgcn_mfma_f32_16x16x32_bf16(af[fm], bf[fn], acc[fm][fn], 0, 0, 0);
    }
    __syncthreads();
    buf ^= 1;
  }

  float c = 1.0f;
  if (in_max != nullptr) {
    int e;
    (void)frexpf(*in_max, &e);
    c = ldexpf(1.0f, -e);  // exact power of two
  }
  const float c2 = c * c;
  float lmax = 0.0f;
#pragma unroll
  for (int fm = 0; fm < 2; ++fm) {
#pragma unroll
    for (int fn = 0; fn < 2; ++fn) {
      const int ocol = bn0 + wc * 32 + fn * 16 + r;
#pragma unroll
      for (int q = 0; q < 4; ++q) {
        const int orow = bm0 + wr * 32 + fm * 16 + g * 4 + q;
        float v = acc[fm][fn][q] * c2;
        Out[(size_t)orow * DDIM + ocol] = f2bf(v);
        lmax = fmaxf(lmax, fabsf(v));
      }
    }
  }
#pragma unroll
  for (int off = 32; off > 0; off >>= 1) lmax = fmaxf(lmax, __shfl_down(lmax, off));
  if (lane == 0) redw[wid] = lmax;
  __syncthreads();
  if (tid == 0) {
    float m = fmaxf(fmaxf(redw[0], redw[1]), fmaxf(redw[2], redw[3]));
    atomicMax((unsigned int*)out_max, __float_as_uint(m));
  }
}

// WT[n][k] = bf16(W[k][n])
__global__ void __launch_bounds__(256)
transpose_bf16(const float* __restrict__ W, unsigned short* __restrict__ WT)
{
  __shared__ float tile[64][65];
  const int bx = blockIdx.x & 15;
  const int by = blockIdx.x >> 4;
  const int tid = threadIdx.x;
  const int c = tid & 63;
  const int r0 = tid >> 6;
#pragma unroll
  for (int p = 0; p < 16; ++p) {
    int kr = p * 4 + r0;
    tile[kr][c] = W[(size_t)(bx * 64 + kr) * DDIM + by * 64 + c];
  }
  __syncthreads();
#pragma unroll
  for (int p = 0; p < 16; ++p) {
    int nr = p * 4 + r0;
    WT[(size_t)(by * 64 + nr) * DDIM + bx * 64 + c] = f2bf(tile[c][nr]);
  }
}

// vout[j] = 2^-12 * sum_i vin[i] * P[j][i]   (P symmetric bf16 1024x1024)
__global__ void __launch_bounds__(256)
gemv_pow(const unsigned short* __restrict__ P, const float* __restrict__ vin,
         float* __restrict__ vout)
{
  const int tid = threadIdx.x;
  const int lane = tid & 63;
  const int wid = tid >> 6;
  float vs[16];
  const float4* vv = (const float4*)(vin + lane * 16);
#pragma unroll
  for (int i = 0; i < 4; ++i) {
    float4 t = vv[i];
    vs[i * 4 + 0] = t.x; vs[i * 4 + 1] = t.y; vs[i * 4 + 2] = t.z; vs[i * 4 + 3] = t.w;
  }
#pragma unroll
  for (int rr = 0; rr < 4; ++rr) {
    const int row = (int)blockIdx.x * 16 + wid * 4 + rr;
    const unsigned short* pr = P + (size_t)row * DDIM + lane * 16;
    short8 p0 = *(const short8*)pr;
    short8 p1 = *(const short8*)(pr + 8);
    float s = 0.f;
#pragma unroll
    for (int e = 0; e < 8; ++e) s += bf2f((unsigned short)p0[e]) * vs[e];
#pragma unroll
    for (int e = 0; e < 8; ++e) s += bf2f((unsigned short)p1[e]) * vs[8 + e];
#pragma unroll
    for (int off = 32; off > 0; off >>= 1) s += __shfl_down(s, off);
    if (lane == 0) vout[row] = s * 0x1p-12f;
  }
}

// v_un[i] = sum_j d[j] * W[i][j]; per-block ssq partial -> vpart[bid]
__global__ void __launch_bounds__(256)
v_kernel(const float* __restrict__ W, const float* __restrict__ d,
         float* __restrict__ v_un, float* __restrict__ vpart)
{
  __shared__ float wsum[4];
  const int tid = threadIdx.x;
  const int lane = tid & 63;
  const int wid = tid >> 6;
  float vs[16];
  const float4* dv = (const float4*)(d + lane * 16);
#pragma unroll
  for (int i = 0; i < 4; ++i) {
    float4 t = dv[i];
    vs[i * 4 + 0] = t.x; vs[i * 4 + 1] = t.y; vs[i * 4 + 2] = t.z; vs[i * 4 + 3] = t.w;
  }
  float ssq = 0.f;
#pragma unroll
  for (int rr = 0; rr < 4; ++rr) {
    const int row = (int)blockIdx.x * 16 + wid * 4 + rr;
    const float4* wrow = (const float4*)(W + (size_t)row * DDIM + lane * 16);
    float s = 0.f;
#pragma unroll
    for (int i = 0; i < 4; ++i) {
      float4 t = wrow[i];
      s += t.x * vs[i * 4 + 0] + t.y * vs[i * 4 + 1] + t.z * vs[i * 4 + 2] + t.w * vs[i * 4 + 3];
    }
#pragma unroll
    for (int off = 32; off > 0; off >>= 1) s += __shfl_down(s, off);
    if (lane == 0) { v_un[row] = s; ssq += s * s; }
  }
  if (lane == 0) wsum[wid] = ssq;
  __syncthreads();
  if (tid == 0) vpart[blockIdx.x] = (wsum[0] + wsum[1]) + (wsum[2] + wsum[3]);
}

// t[j] = sum_i v_un[i]*W[i][j]; tpart[bid] = ssq over this block's 32 cols.
// Last-arriving block (atomic ticket) computes sigma -> inv (merged finalize).
__global__ void __launch_bounds__(256)
t_fin_kernel(const float* __restrict__ W, const float* __restrict__ v_un,
             float* __restrict__ vpart, float* __restrict__ tpart,
             unsigned int* __restrict__ counter, float* __restrict__ inv_out)
{
  __shared__ float part[8][33];
  __shared__ unsigned int sticket;
  const int tid = threadIdx.x;
  const int col = (int)blockIdx.x * 32 + (tid & 31);
  const int ch = tid >> 5;
  float s = 0.f;
  const int i0 = ch * 128;
  for (int i = i0; i < i0 + 128; ++i)
    s += v_un[i] * W[(size_t)i * DDIM + col];
  part[ch][tid & 31] = s;
  __syncthreads();
  if (tid < 32) {
    float t = 0.f;
#pragma unroll
    for (int c2 = 0; c2 < 8; ++c2) t += part[c2][tid];
    part[0][tid] = t * t;
  }
  __syncthreads();
  if (tid == 0) {
    float ss = 0.f;
#pragma unroll
    for (int c = 0; c < 32; ++c) ss += part[0][c];
    tpart[blockIdx.x] = ss;
    __threadfence();
    sticket = atomicAdd(counter, 1u);
  }
  __syncthreads();
  if (sticket == 31) {  // last block: finalize
    __threadfence();
    float val = 0.f;
    if (tid < 64)
      val = __uint_as_float(atomicOr((unsigned int*)&vpart[tid], 0u));
    part[tid >> 5][tid & 31] = val;
    __syncthreads();
    if (tid == 0) {
      float sv = 0.f;
      for (int i = 0; i < 64; ++i) sv += part[i >> 5][i & 31];
      float stq = 0.f;
      for (int i = 0; i < 32; ++i)
        stq += __uint_as_float(atomicOr((unsigned int*)&tpart[i], 0u));
      float sigma = sqrtf(stq / sv);
      inv_out[0] = (sigma > 0.9f) ? (0.9f / sigma) : 1.0f;
    }
  }
}

extern "C" void kernel_launch(void* const* d_in, const int* in_sizes, int n_in,
                              void* d_out, int out_size, void* d_ws, size_t ws_size,
                              hipStream_t stream)
{
  const float* x  = (const float*)d_in[0];
  const float* w  = (const float*)d_in[1];
  const float* b  = (const float*)d_in[2];
  const float* u0 = (const float*)d_in[3];
  float* out = (float*)d_out;

  char* ws = (char*)d_ws;
  float* scal = (float*)ws;  // [0..5] max chain, [8] inv, [16..79] vpart,
                             // [80..111] tpart, [120] ticket counter
  float* u_a  = (float*)(ws + 0x1000);
  float* u_b  = (float*)(ws + 0x2000);
  float* v_un = (float*)(ws + 0x3000);
  unsigned short* WT = (unsigned short*)(ws + 0x4000);
  unsigned short* P0 = (unsigned short*)(ws + 0x204000);
  unsigned short* P1 = (unsigned short*)(ws + 0x404000);

  hipMemsetAsync(d_ws, 0, 4096, stream);
  hipLaunchKernelGGL(transpose_bf16, dim3(256), dim3(256), 0, stream, w, WT);

  // M = W^T W, then square up to M^32   (64x64 tiles -> grid 256)
  hipLaunchKernelGGL(sq_gemm, dim3(256), dim3(256), 0, stream,
                     WT, WT, P0, (const float*)nullptr, &scal[0]);          // M
  hipLaunchKernelGGL(sq_gemm, dim3(256), dim3(256), 0, stream,
                     P0, P0, P1, &scal[0], &scal[1]);                       // M^2
  hipLaunchKernelGGL(sq_gemm, dim3(256), dim3(256), 0, stream,
                     P1, P1, P0, &scal[1], &scal[2]);                       // M^4
  hipLaunchKernelGGL(sq_gemm, dim3(256), dim3(256), 0, stream,
                     P0, P0, P1, &scal[2], &scal[3]);                       // M^8
  hipLaunchKernelGGL(sq_gemm, dim3(256), dim3(256), 0, stream,
                     P1, P1, P0, &scal[3], &scal[4]);                       // M^16
  hipLaunchKernelGGL(sq_gemm, dim3(256), dim3(256), 0, stream,
                     P0, P0, P1, &scal[4], &scal[5]);                       // M^32 -> P1

  // u = u0 * (M^32)^3  (direction of u0 M^96)
  hipLaunchKernelGGL(gemv_pow, dim3(64), dim3(256), 0, stream, P1, u0, u_a);
  hipLaunchKernelGGL(gemv_pow, dim3(64), dim3(256), 0, stream, P1, u_a, u_b);
  hipLaunchKernelGGL(gemv_pow, dim3(64), dim3(256), 0, stream, P1, u_b, u_a);

  hipLaunchKernelGGL(v_kernel, dim3(64), dim3(256), 0, stream, w, u_a, v_un, &scal[16]);
  hipLaunchKernelGGL(t_fin_kernel, dim3(32), dim3(256), 0, stream,
                     w, v_un, &scal[16], &scal[80],
                     (unsigned int*)&scal[120], &scal[8]);

  // out = (x @ W) * inv + b   (BM=128 x BN=256, m-major, 1-deep dbuf)
  hipLaunchKernelGGL(big_gemm, dim3(1024), dim3(512), 0, stream,
                     x, WT, out, &scal[8], b);
}